// Round 10
// baseline (447.182 us; speedup 1.0000x reference)
//
#include <hip/hip_runtime.h>
#include <hip/hip_bf16.h>

#define N_NODES     65536
#define N_EDGES     524288
#define N_GRAPHS    512
#define G_NODES_N   10000
#define NUM_DIS     2000
#define IN_DIM      128
#define HID         256
#define D_FEAT      512
#define MAX_Z       4000
#define POOL_SPLIT  8

typedef _Float16 half8 __attribute__((ext_vector_type(8)));
typedef float    f32x4 __attribute__((ext_vector_type(4)));

typedef __attribute__((address_space(1))) const void as1_void;
typedef __attribute__((address_space(3))) void       as3_void;

// ---------------------------------------------------------------------------
// 1. ONE prep dispatch: all weight converts/swizzles + zt16 + zn2 + zeroing.
//    blocks [0,32): Ws/Wn 64x64-tile transpose   [32,64): Wd/Wc transpose
//    [64,576): W12P swizzle  [576,826): z_table->f16  [826,890): zero cnt(+flags)
//    [890,1146): pack zn2 = {z, node_id}
// ---------------------------------------------------------------------------
__global__ __launch_bounds__(256) void prep_kernel(
    const float* __restrict__ Ws, const float* __restrict__ Wn,
    const float* __restrict__ Wd, const float* __restrict__ Wc,
    const float* __restrict__ W1, const float* __restrict__ W2,
    const float* __restrict__ z_table,
    const int* __restrict__ z, const int* __restrict__ node_id,
    _Float16* __restrict__ WsT, _Float16* __restrict__ WnT,
    _Float16* __restrict__ WdT, _Float16* __restrict__ WcT,
    _Float16* __restrict__ W12P, _Float16* __restrict__ zt16,
    int2* __restrict__ zn2, int* __restrict__ cnt, int* __restrict__ flags)
{
    const int b = blockIdx.x;
    const int tid = threadIdx.x;
    if (b < 64) {
        __shared__ float tile[64][65];
        const float* W; _Float16* T; int K, N, k0, n0;
        if (b < 32) {
            const int mat = b >> 4, t = b & 15;
            K = HID; N = HID; k0 = (t >> 2) * 64; n0 = (t & 3) * 64;
            W = (mat == 0) ? Ws : Wn;
            T = (mat == 0) ? WsT : WnT;
        } else {
            const int bb = b - 32;
            const int mat = bb >> 4, t = bb & 15;
            K = D_FEAT; N = IN_DIM; k0 = (t >> 1) * 64; n0 = (t & 1) * 64;
            W = (mat == 0) ? Wd : Wc;
            T = (mat == 0) ? WdT : WcT;
        }
        const int tx = tid & 63, ty = tid >> 6;
        #pragma unroll
        for (int r = 0; r < 64; r += 4)
            tile[r + ty][tx] = W[(size_t)(k0 + r + ty) * N + n0 + tx];
        __syncthreads();
        #pragma unroll
        for (int c = 0; c < 64; c += 4)
            T[(size_t)(n0 + c + ty) * K + k0 + tx] = (_Float16)tile[tx][c + ty];
    } else if (b < 576) {
        const int bb = b - 64;              // 0..511
        const int mat = bb >> 8;            // 0: W1, 1: W2
        const int k = bb & 255;
        const int n = tid;
        const float* W = mat ? W2 : W1;
        const float v = W[(size_t)k * HID + n];
        const size_t idx = (size_t)(mat * 8 + (k >> 5)) * 8192
                         + (size_t)((((k >> 3) & 3) * 256 + n) * 8 + (k & 7));
        W12P[idx] = (_Float16)v;
    } else if (b < 826) {
        const size_t base = ((size_t)(b - 576) * 256 + tid) * 8;  // < 512000
        const float4 f0 = *(const float4*)(z_table + base);
        const float4 f1 = *(const float4*)(z_table + base + 4);
        half8 h;
        h[0]=(_Float16)f0.x; h[1]=(_Float16)f0.y; h[2]=(_Float16)f0.z; h[3]=(_Float16)f0.w;
        h[4]=(_Float16)f1.x; h[5]=(_Float16)f1.y; h[6]=(_Float16)f1.z; h[7]=(_Float16)f1.w;
        *(half8*)(zt16 + base) = h;
    } else if (b < 890) {
        const int base = (b - 826) * 1024 + tid * 4;
        *(int4*)(cnt + base) = make_int4(0, 0, 0, 0);
        if (b == 826 && tid < 128) flags[tid] = 0;
    } else {
        const int i = (b - 890) * 256 + tid;
        zn2[i] = make_int2(z[i], node_id[i]);
    }
}

// ---------------------------------------------------------------------------
// 2. Projection GEMM (MFMA), both segments in one dispatch.
// ---------------------------------------------------------------------------
__global__ __launch_bounds__(256) void proj_mfma_kernel(
    const float* __restrict__ dtab, const float* __restrict__ ctab,
    const _Float16* __restrict__ WdT, const _Float16* __restrict__ WcT,
    _Float16* __restrict__ proj)
{
    __shared__ _Float16 Alds[128 * 40];
    __shared__ _Float16 Blds[128 * 40];
    const int blk = blockIdx.x;
    const float* tab; const _Float16* WT; int base, M, bm;
    if (blk < 16) { tab = dtab; WT = WdT; base = 0;           M = NUM_DIS + 1;             bm = blk * 128; }
    else          { tab = ctab; WT = WcT; base = NUM_DIS + 1; M = G_NODES_N - NUM_DIS - 1; bm = (blk - 16) * 128; }
    const int tid  = threadIdx.x;
    const int wave = tid >> 6, lane = tid & 63;
    const int q    = lane >> 4, l16 = lane & 15;
    const int mbase = (wave & 1) * 64, nbase = (wave >> 1) * 64;
    const int r = tid >> 1, s = tid & 1;

    f32x4 acc[4][4] = {};

    for (int kc = 0; kc < 16; ++kc) {
        const int k0 = kc * 32;
        const int arow = min(bm + r, M - 1);
        const float* gA = tab + (size_t)(base + arow) * D_FEAT + k0 + s * 16;
        const _Float16* gB = WT + (size_t)r * D_FEAT + k0 + s * 16;
        const float4 f0 = ((const float4*)gA)[0];
        const float4 f1 = ((const float4*)gA)[1];
        const float4 f2 = ((const float4*)gA)[2];
        const float4 f3 = ((const float4*)gA)[3];
        const half8 hb0 = *(const half8*)gB;
        const half8 hb1 = *(const half8*)(gB + 8);
        half8 h0, h1;
        h0[0]=(_Float16)f0.x; h0[1]=(_Float16)f0.y; h0[2]=(_Float16)f0.z; h0[3]=(_Float16)f0.w;
        h0[4]=(_Float16)f1.x; h0[5]=(_Float16)f1.y; h0[6]=(_Float16)f1.z; h0[7]=(_Float16)f1.w;
        h1[0]=(_Float16)f2.x; h1[1]=(_Float16)f2.y; h1[2]=(_Float16)f2.z; h1[3]=(_Float16)f2.w;
        h1[4]=(_Float16)f3.x; h1[5]=(_Float16)f3.y; h1[6]=(_Float16)f3.z; h1[7]=(_Float16)f3.w;
        __syncthreads();
        *(half8*)&Alds[r * 40 + s * 16]     = h0;
        *(half8*)&Alds[r * 40 + s * 16 + 8] = h1;
        *(half8*)&Blds[r * 40 + s * 16]     = hb0;
        *(half8*)&Blds[r * 40 + s * 16 + 8] = hb1;
        __syncthreads();
        half8 a[4], b[4];
        #pragma unroll
        for (int i = 0; i < 4; ++i)
            a[i] = *(const half8*)&Alds[(mbase + i * 16 + l16) * 40 + q * 8];
        #pragma unroll
        for (int j = 0; j < 4; ++j)
            b[j] = *(const half8*)&Blds[(nbase + j * 16 + l16) * 40 + q * 8];
        #pragma unroll
        for (int i = 0; i < 4; ++i)
            #pragma unroll
            for (int j = 0; j < 4; ++j)
                acc[i][j] = __builtin_amdgcn_mfma_f32_16x16x32_f16(a[i], b[j], acc[i][j], 0, 0, 0);
    }

    #pragma unroll
    for (int j = 0; j < 4; ++j) {
        const int colg = nbase + j * 16 + l16;   // 0..127
        #pragma unroll
        for (int i = 0; i < 4; ++i) {
            #pragma unroll
            for (int rr = 0; rr < 4; ++rr) {
                const int row = bm + mbase + i * 16 + q * 4 + rr;
                if (row < M)
                    proj[(size_t)(base + row) * IN_DIM + colg] = (_Float16)acc[i][j][rr];
            }
        }
    }
}

// ---------------------------------------------------------------------------
// 3. CSR build: hist -> fused decoupled-lookback scan -> scatter
// ---------------------------------------------------------------------------
__global__ __launch_bounds__(256) void hist_kernel(
    const int* __restrict__ dst, int* __restrict__ cnt)
{
    const int e = blockIdx.x * 256 + threadIdx.x;
    if (e < N_EDGES) atomicAdd(&cnt[dst[e]], 1);
}

// 64 blocks. flags[0..63] = ready flags, flags[64..127] = inclusive prefixes.
__global__ __launch_bounds__(256) void scan_fused_kernel(
    const int* __restrict__ cnt, int* __restrict__ row_ptr,
    int* __restrict__ fill, int* __restrict__ flags)
{
    __shared__ int a[256], b[256];
    __shared__ int segbase;
    const int t = threadIdx.x;
    const int blk = blockIdx.x;
    const int base = blk * 1024 + t * 4;
    const int4 c = *(const int4*)(cnt + base);
    const int s = c.x + c.y + c.z + c.w;
    a[t] = s;
    __syncthreads();
    int* in = a; int* out = b;
    for (int off = 1; off < 256; off <<= 1) {
        out[t] = in[t] + ((t >= off) ? in[t - off] : 0);
        __syncthreads();
        int* tmp = in; in = out; out = tmp;
    }
    if (t == 255) {
        const int blocksum = in[255];
        int pfx = 0;
        if (blk > 0) {
            while (atomicAdd(&flags[blk - 1], 0) == 0) {}
            pfx = atomicAdd(&flags[64 + blk - 1], 0);
        }
        atomicExch(&flags[64 + blk], pfx + blocksum);
        __threadfence();
        atomicExch(&flags[blk], 1);
        segbase = pfx;
        if (blk == 63) row_ptr[N_NODES] = pfx + blocksum;
    }
    __syncthreads();
    const int run = in[t] - s + segbase;
    int4 r;
    r.x = run; r.y = run + c.x; r.z = r.y + c.y; r.w = r.z + c.z;
    *(int4*)(row_ptr + base) = r;
    *(int4*)(fill + base) = r;
}

__global__ __launch_bounds__(256) void scatter_kernel(
    const int* __restrict__ src, const int* __restrict__ dst,
    int* __restrict__ fill, int* __restrict__ col)
{
    const int e = blockIdx.x * 256 + threadIdx.x;
    if (e < N_EDGES) {
        const int pos = atomicAdd(&fill[dst[e]], 1);
        col[pos] = src[e];
    }
}

// ---------------------------------------------------------------------------
// 4. Fused GIN: table-gather aggregation + both GIN GEMMs, H1 stays in LDS.
//    Gather sources are f16 + L2-resident: zt16 (1MB) + proj (2.5MB) + zn2.
// ---------------------------------------------------------------------------
__global__ __launch_bounds__(256) void gin_fused_kernel(
    const int* __restrict__ row_ptr, const int* __restrict__ colv,
    const int2* __restrict__ zn2,
    const _Float16* __restrict__ zt16, const _Float16* __restrict__ proj,
    const _Float16* __restrict__ W12P,
    const float* __restrict__ b1, const float* __restrict__ b2,
    _Float16* __restrict__ H)
{
    __shared__ _Float16 Apanel[32 * 264];   // [row][k], pad 264
    __shared__ _Float16 Blds[2][8192];      // [ks4][n256][8]

    const int bm   = blockIdx.x * 32;
    const int tid  = threadIdx.x;
    const int wave = tid >> 6, lane = tid & 63;
    const int q    = lane >> 4, l16 = lane & 15;
    const int nbase = wave * 64;

    auto stage = [&](int c, int buf) {
        const _Float16* src = W12P + (size_t)c * 8192;
        #pragma unroll
        for (int tt = 0; tt < 4; ++tt) {
            const int seg = (wave * 4 + tt) * 64 + lane;
            __builtin_amdgcn_global_load_lds((as1_void*)(src + seg * 8),
                (as3_void*)&Blds[buf][(wave * 4 + tt) * 64 * 8], 16, 0, 0);
        }
    };

    stage(0, 0);   // chunk-0 DMA overlaps the gather phase

    // ---- phase 0: gather (self + neighbor sum), all-f16 sources ----
    {
        const int r = tid >> 3, p = tid & 7;    // row 0..31, dim-slice 0..7
        const int gr = bm + r;
        const int beg = row_ptr[gr], end = row_ptr[gr + 1];
        float za[16], pa[16];
        {
            const int2 zn = zn2[gr];
            const half8* zp = (const half8*)(zt16 + (size_t)zn.x * IN_DIM + p * 16);
            const half8* pp = (const half8*)(proj + (size_t)zn.y * IN_DIM + p * 16);
            const half8 z0 = zp[0], z1 = zp[1], p0 = pp[0], p1 = pp[1];
            #pragma unroll
            for (int i = 0; i < 8; ++i) {
                za[i] = (float)z0[i]; za[8 + i] = (float)z1[i];
                pa[i] = (float)p0[i]; pa[8 + i] = (float)p1[i];
            }
        }
        for (int e = beg; e < end; ++e) {
            const int2 zn = zn2[colv[e]];
            const half8* zp = (const half8*)(zt16 + (size_t)zn.x * IN_DIM + p * 16);
            const half8* pp = (const half8*)(proj + (size_t)zn.y * IN_DIM + p * 16);
            const half8 z0 = zp[0], z1 = zp[1], p0 = pp[0], p1 = pp[1];
            #pragma unroll
            for (int i = 0; i < 8; ++i) {
                za[i] += (float)z0[i]; za[8 + i] += (float)z1[i];
                pa[i] += (float)p0[i]; pa[8 + i] += (float)p1[i];
            }
        }
        half8 oz0, oz1, op0, op1;
        #pragma unroll
        for (int i = 0; i < 8; ++i) {
            oz0[i] = (_Float16)za[i];     oz1[i] = (_Float16)za[8 + i];
            op0[i] = (_Float16)pa[i];     op1[i] = (_Float16)pa[8 + i];
        }
        *(half8*)&Apanel[r * 264 + p * 16]           = oz0;
        *(half8*)&Apanel[r * 264 + p * 16 + 8]       = oz1;
        *(half8*)&Apanel[r * 264 + 128 + p * 16]     = op0;
        *(half8*)&Apanel[r * 264 + 128 + p * 16 + 8] = op1;
    }
    __syncthreads();   // gather visible + chunk-0 DMA drained

    f32x4 acc[2][4] = {};
    int pb = 0;
    for (int c = 0; c < 16; ++c) {
        if (c + 1 < 16) stage(c + 1, pb ^ 1);
        if (c == 8) {
            #pragma unroll
            for (int j = 0; j < 4; ++j) {
                const int colg = nbase + j * 16 + l16;
                const float bv = b1[colg];
                #pragma unroll
                for (int i = 0; i < 2; ++i)
                    #pragma unroll
                    for (int rr = 0; rr < 4; ++rr) {
                        const float v = fmaxf(acc[i][j][rr] + bv, 0.0f);
                        Apanel[(i * 16 + q * 4 + rr) * 264 + colg] = (_Float16)v;
                        acc[i][j][rr] = 0.0f;
                    }
            }
            __syncthreads();
        }
        const int kl = (c & 7) * 32;
        half8 a[2], b[4];
        #pragma unroll
        for (int i = 0; i < 2; ++i)
            a[i] = *(const half8*)&Apanel[(i * 16 + l16) * 264 + kl + q * 8];
        #pragma unroll
        for (int j = 0; j < 4; ++j)
            b[j] = *(const half8*)&Blds[pb][(q * 256 + nbase + j * 16 + l16) * 8];
        #pragma unroll
        for (int i = 0; i < 2; ++i)
            #pragma unroll
            for (int j = 0; j < 4; ++j)
                acc[i][j] = __builtin_amdgcn_mfma_f32_16x16x32_f16(a[i], b[j], acc[i][j], 0, 0, 0);
        __syncthreads();
        pb ^= 1;
    }

    #pragma unroll
    for (int j = 0; j < 4; ++j) {
        const int colg = nbase + j * 16 + l16;
        const float bv = b2[colg];
        #pragma unroll
        for (int i = 0; i < 2; ++i)
            #pragma unroll
            for (int rr = 0; rr < 4; ++rr) {
                const int rowg = bm + i * 16 + q * 4 + rr;
                H[(size_t)rowg * HID + colg] = (_Float16)(acc[i][j][rr] + bv);
            }
    }
}

// ---------------------------------------------------------------------------
// 5. CSR gather-aggregation (SAGE mean): 32 lanes/row (16B loads).
// ---------------------------------------------------------------------------
__global__ __launch_bounds__(256) void csr_agg_kernel(
    const int* __restrict__ row_ptr, const int* __restrict__ col,
    const _Float16* __restrict__ F, _Float16* __restrict__ OUT)
{
    const int t = blockIdx.x * 256 + threadIdx.x;
    const int d = t >> 5;
    const int q = t & 31;
    const int beg = row_ptr[d];
    const int end = row_ptr[d + 1];
    float acc[8] = {0.f,0.f,0.f,0.f,0.f,0.f,0.f,0.f};
    int e = beg;
    for (; e + 4 <= end; e += 4) {
        const int s0 = col[e],     s1 = col[e + 1];
        const int s2 = col[e + 2], s3 = col[e + 3];
        const half8 v0 = *(const half8*)(F + (size_t)s0 * HID + q * 8);
        const half8 v1 = *(const half8*)(F + (size_t)s1 * HID + q * 8);
        const half8 v2 = *(const half8*)(F + (size_t)s2 * HID + q * 8);
        const half8 v3 = *(const half8*)(F + (size_t)s3 * HID + q * 8);
        #pragma unroll
        for (int i = 0; i < 8; ++i)
            acc[i] += ((float)v0[i] + (float)v1[i]) + ((float)v2[i] + (float)v3[i]);
    }
    for (; e < end; ++e) {
        const half8 v0 = *(const half8*)(F + (size_t)col[e] * HID + q * 8);
        #pragma unroll
        for (int i = 0; i < 8; ++i) acc[i] += (float)v0[i];
    }
    const float rs = 1.0f / fmaxf((float)(end - beg), 1.0f);
    half8 o;
    #pragma unroll
    for (int i = 0; i < 8; ++i) o[i] = (_Float16)(acc[i] * rs);
    *(half8*)(OUT + (size_t)d * HID + q * 8) = o;
}

// ---------------------------------------------------------------------------
// 6. MFMA f16 GEMM (SAGE): C = [A1|A2] @ [B1;B2] + bias, K=512 -> f16
// ---------------------------------------------------------------------------
__global__ __launch_bounds__(256) void mfma_gemm_kernel(
    const _Float16* __restrict__ A1, const _Float16* __restrict__ A2,
    const _Float16* __restrict__ B1T, const _Float16* __restrict__ B2T,
    const float* __restrict__ bias, _Float16* __restrict__ Ch)
{
    __shared__ _Float16 Alds[128 * 32];
    __shared__ _Float16 Blds[128 * 32];
    const int bm   = blockIdx.x * 128;
    const int bn   = blockIdx.y * 128;
    const int tid  = threadIdx.x;
    const int wave = tid >> 6, lane = tid & 63;
    const int q    = lane >> 4, l16 = lane & 15;
    const int mbase = (wave & 1) * 64, nbase = (wave >> 1) * 64;

    f32x4 acc[4][4] = {};

    for (int kc = 0; kc < 16; ++kc) {
        const int k0 = (kc & 7) * 32;
        const _Float16* Abase = (kc < 8) ? A1 : A2;
        const _Float16* Bbase = (kc < 8) ? B1T : B2T;
        __syncthreads();
        #pragma unroll
        for (int t = 0; t < 2; ++t) {
            const int i   = wave * 128 + t * 64 + lane;
            const int row = i >> 2, s = i & 3;
            const _Float16* gA = Abase + (size_t)(bm + row) * HID + k0 + s * 8;
            const _Float16* gB = Bbase + (size_t)(bn + row) * HID + k0 + s * 8;
            __builtin_amdgcn_global_load_lds(
                (as1_void*)gA, (as3_void*)&Alds[(wave * 128 + t * 64) * 8], 16, 0, 0);
            __builtin_amdgcn_global_load_lds(
                (as1_void*)gB, (as3_void*)&Blds[(wave * 128 + t * 64) * 8], 16, 0, 0);
        }
        __syncthreads();
        half8 a[4], b[4];
        #pragma unroll
        for (int i = 0; i < 4; ++i)
            a[i] = *(const half8*)&Alds[(mbase + i * 16 + l16) * 32 + q * 8];
        #pragma unroll
        for (int j = 0; j < 4; ++j)
            b[j] = *(const half8*)&Blds[(nbase + j * 16 + l16) * 32 + q * 8];
        #pragma unroll
        for (int i = 0; i < 4; ++i)
            #pragma unroll
            for (int j = 0; j < 4; ++j)
                acc[i][j] = __builtin_amdgcn_mfma_f32_16x16x32_f16(a[i], b[j], acc[i][j], 0, 0, 0);
    }

    #pragma unroll
    for (int j = 0; j < 4; ++j) {
        const int colg = bn + nbase + j * 16 + l16;
        const float bv = bias[colg];
        #pragma unroll
        for (int i = 0; i < 4; ++i) {
            #pragma unroll
            for (int rr = 0; rr < 4; ++rr) {
                const int rowg = bm + mbase + i * 16 + q * 4 + rr;
                Ch[(size_t)rowg * HID + colg] = (_Float16)(acc[i][j][rr] + bv);
            }
        }
    }
}

// ---------------------------------------------------------------------------
// 7a. Parallel partial max-pool.
// ---------------------------------------------------------------------------
__global__ __launch_bounds__(256) void pool_part_kernel(
    const _Float16* __restrict__ H2, const int* __restrict__ gid,
    float* __restrict__ Gpart)
{
    const int g = blockIdx.y;
    const int sp = blockIdx.x;
    const int j = threadIdx.x;
    int lo = 0, hi = N_NODES;
    while (lo < hi) { const int mid = (lo + hi) >> 1; if (gid[mid] < g) lo = mid + 1; else hi = mid; }
    const int start = lo;
    hi = N_NODES;
    while (lo < hi) { const int mid = (lo + hi) >> 1; if (gid[mid] < g + 1) lo = mid + 1; else hi = mid; }
    const int end = lo;
    float m = -INFINITY;
    for (int i = start + sp; i < end; i += POOL_SPLIT)
        m = fmaxf(m, (float)H2[(size_t)i * HID + j]);
    Gpart[((size_t)g * POOL_SPLIT + sp) * HID + j] = m;
}

// ---------------------------------------------------------------------------
// 7b. Head: reduce partials + MLP.
// ---------------------------------------------------------------------------
__global__ __launch_bounds__(256) void head_kernel(
    const float* __restrict__ Gpart,
    const float* __restrict__ W1, const float* __restrict__ b1,
    const float* __restrict__ W2, const float* __restrict__ b2,
    float* __restrict__ out)
{
    const int g = blockIdx.x;
    const int j = threadIdx.x;
    __shared__ float row[HID];
    __shared__ float red[HID];
    float m = -INFINITY;
    #pragma unroll
    for (int sp = 0; sp < POOL_SPLIT; ++sp)
        m = fmaxf(m, Gpart[((size_t)g * POOL_SPLIT + sp) * HID + j]);
    row[j] = (m == -INFINITY) ? 0.0f : m;
    __syncthreads();
    float acc = b1[j];
    #pragma unroll 8
    for (int k = 0; k < HID; ++k)
        acc = fmaf(row[k], W1[k * HID + j], acc);
    acc = fmaxf(acc, 0.f);
    red[j] = acc * W2[j];
    __syncthreads();
    for (int s = 128; s > 0; s >>= 1) {
        if (j < s) red[j] += red[j + s];
        __syncthreads();
    }
    if (j == 0) out[g] = red[0] + b2[0];
}

// ---------------------------------------------------------------------------
extern "C" void kernel_launch(void* const* d_in, const int* in_sizes, int n_in,
                              void* d_out, int out_size, void* d_ws, size_t ws_size,
                              hipStream_t stream)
{
    const int*   z         = (const int*)d_in[0];
    const int*   node_id   = (const int*)d_in[1];
    const int*   src       = (const int*)d_in[2];
    const int*   dst       = (const int*)d_in[3];
    const int*   graph_ids = (const int*)d_in[4];
    const float* z_table   = (const float*)d_in[5];
    const float* d_feat    = (const float*)d_in[6];
    const float* c_feat    = (const float*)d_in[7];
    const float* Wd        = (const float*)d_in[8];
    const float* Wc        = (const float*)d_in[9];
    const float* gin_W1    = (const float*)d_in[10];
    const float* gin_b1    = (const float*)d_in[11];
    const float* gin_W2    = (const float*)d_in[12];
    const float* gin_b2    = (const float*)d_in[13];
    const float* sage_Wself  = (const float*)d_in[14];
    const float* sage_Wneigh = (const float*)d_in[15];
    const float* sage_b    = (const float*)d_in[16];
    const float* lin1_W    = (const float*)d_in[17];
    const float* lin1_b    = (const float*)d_in[18];
    const float* lin2_W    = (const float*)d_in[19];
    const float* lin2_b    = (const float*)d_in[20];
    float* out = (float*)d_out;

    // ---- workspace carve-up ----
    const size_t NH = (size_t)N_NODES * HID;
    char* wsb = (char*)d_ws;
    _Float16* Hh   = (_Float16*)wsb;                     wsb += NH * 2;
    _Float16* AGGh = (_Float16*)wsb;                     wsb += NH * 2;
    _Float16* H2h  = (_Float16*)wsb;                     wsb += NH * 2;
    _Float16* projh= (_Float16*)wsb;                     wsb += (size_t)G_NODES_N * IN_DIM * 2;
    _Float16* W12P = (_Float16*)wsb;                     wsb += 16 * 8192 * 2;
    _Float16* WsT  = (_Float16*)wsb;                     wsb += HID * HID * 2;
    _Float16* WnT  = (_Float16*)wsb;                     wsb += HID * HID * 2;
    _Float16* WdT  = (_Float16*)wsb;                     wsb += D_FEAT * IN_DIM * 2;
    _Float16* WcT  = (_Float16*)wsb;                     wsb += D_FEAT * IN_DIM * 2;
    _Float16* zt16 = (_Float16*)wsb;                     wsb += (size_t)MAX_Z * IN_DIM * 2;
    int2* zn2      = (int2*)wsb;                         wsb += (size_t)N_NODES * 8;
    float* Gpart   = (float*)wsb;                        wsb += (size_t)N_GRAPHS * POOL_SPLIT * HID * 4;
    int* row_ptr   = (int*)wsb;                          wsb += (N_NODES + 4) * 4;
    int* cnt       = (int*)wsb;                          wsb += N_NODES * 4;
    int* fill      = (int*)wsb;                          wsb += N_NODES * 4;
    int* col       = (int*)wsb;                          wsb += N_EDGES * 4;
    int* flags     = (int*)wsb;                          wsb += 128 * 4;

    // ---- prep: all converts/swizzles/zeroing in one dispatch ----
    prep_kernel<<<1146, 256, 0, stream>>>(
        sage_Wself, sage_Wneigh, Wd, Wc, gin_W1, gin_W2, z_table, z, node_id,
        WsT, WnT, WdT, WcT, W12P, zt16, zn2, cnt, flags);

    // ---- CSR build ----
    hist_kernel<<<N_EDGES / 256, 256, 0, stream>>>(dst, cnt);
    scan_fused_kernel<<<64, 256, 0, stream>>>(cnt, row_ptr, fill, flags);
    scatter_kernel<<<N_EDGES / 256, 256, 0, stream>>>(src, dst, fill, col);

    // ---- projection table via MFMA ----
    proj_mfma_kernel<<<16 + 63, 256, 0, stream>>>(d_feat, c_feat, WdT, WcT, projh);

    // ---- fused GIN: gather + MLP, H1 stays in LDS ----
    gin_fused_kernel<<<N_NODES / 32, 256, 0, stream>>>(
        row_ptr, col, zn2, zt16, projh, W12P, gin_b1, gin_b2, Hh);

    // ---- SAGE mean aggregation ----
    csr_agg_kernel<<<(N_NODES * 32) / 256, 256, 0, stream>>>(row_ptr, col, Hh, AGGh);

    // ---- SAGE: H2 = H@Wself + AGG@Wneigh + b  (K=512) ----
    dim3 ggrid(N_NODES / 128, HID / 128);
    mfma_gemm_kernel<<<ggrid, 256, 0, stream>>>(Hh, AGGh, WsT, WnT, sage_b, H2h);

    // ---- parallel max pool + head ----
    dim3 pgrid(POOL_SPLIT, N_GRAPHS);
    pool_part_kernel<<<pgrid, 256, 0, stream>>>(H2h, graph_ids, Gpart);
    head_kernel<<<N_GRAPHS, 256, 0, stream>>>(Gpart, lin1_W, lin1_b, lin2_W, lin2_b, out);
}

// Round 11
// 379.177 us; speedup vs baseline: 1.1793x; 1.1793x over previous
//
#include <hip/hip_runtime.h>
#include <hip/hip_bf16.h>

#define N_NODES     65536
#define N_EDGES     524288
#define N_GRAPHS    512
#define G_NODES_N   10000
#define NUM_DIS     2000
#define IN_DIM      128
#define HID         256
#define D_FEAT      512
#define MAX_Z       4000
#define POOL_SPLIT  8

typedef _Float16 half8 __attribute__((ext_vector_type(8)));
typedef float    f32x4 __attribute__((ext_vector_type(4)));

typedef __attribute__((address_space(1))) const void as1_void;
typedef __attribute__((address_space(3))) void       as3_void;

// ---------------------------------------------------------------------------
// 1. ONE prep dispatch: all weight converts/swizzles + zt16 + zn2 + zeroing.
//    blocks [0,32): Ws/Wn 64x64-tile transpose   [32,64): Wd/Wc transpose
//    [64,576): W12P swizzle  [576,826): z_table->f16  [826,890): zero cnt(+flags)
//    [890,1146): pack zn2 = {z, node_id}
// ---------------------------------------------------------------------------
__global__ __launch_bounds__(256) void prep_kernel(
    const float* __restrict__ Ws, const float* __restrict__ Wn,
    const float* __restrict__ Wd, const float* __restrict__ Wc,
    const float* __restrict__ W1, const float* __restrict__ W2,
    const float* __restrict__ z_table,
    const int* __restrict__ z, const int* __restrict__ node_id,
    _Float16* __restrict__ WsT, _Float16* __restrict__ WnT,
    _Float16* __restrict__ WdT, _Float16* __restrict__ WcT,
    _Float16* __restrict__ W12P, _Float16* __restrict__ zt16,
    int2* __restrict__ zn2, int* __restrict__ cnt, int* __restrict__ flags)
{
    const int b = blockIdx.x;
    const int tid = threadIdx.x;
    if (b < 64) {
        __shared__ float tile[64][65];
        const float* W; _Float16* T; int K, N, k0, n0;
        if (b < 32) {
            const int mat = b >> 4, t = b & 15;
            K = HID; N = HID; k0 = (t >> 2) * 64; n0 = (t & 3) * 64;
            W = (mat == 0) ? Ws : Wn;
            T = (mat == 0) ? WsT : WnT;
        } else {
            const int bb = b - 32;
            const int mat = bb >> 4, t = bb & 15;
            K = D_FEAT; N = IN_DIM; k0 = (t >> 1) * 64; n0 = (t & 1) * 64;
            W = (mat == 0) ? Wd : Wc;
            T = (mat == 0) ? WdT : WcT;
        }
        const int tx = tid & 63, ty = tid >> 6;
        #pragma unroll
        for (int r = 0; r < 64; r += 4)
            tile[r + ty][tx] = W[(size_t)(k0 + r + ty) * N + n0 + tx];
        __syncthreads();
        #pragma unroll
        for (int c = 0; c < 64; c += 4)
            T[(size_t)(n0 + c + ty) * K + k0 + tx] = (_Float16)tile[tx][c + ty];
    } else if (b < 576) {
        const int bb = b - 64;              // 0..511
        const int mat = bb >> 8;            // 0: W1, 1: W2
        const int k = bb & 255;
        const int n = tid;
        const float* W = mat ? W2 : W1;
        const float v = W[(size_t)k * HID + n];
        const size_t idx = (size_t)(mat * 8 + (k >> 5)) * 8192
                         + (size_t)((((k >> 3) & 3) * 256 + n) * 8 + (k & 7));
        W12P[idx] = (_Float16)v;
    } else if (b < 826) {
        const size_t base = ((size_t)(b - 576) * 256 + tid) * 8;  // < 512000
        const float4 f0 = *(const float4*)(z_table + base);
        const float4 f1 = *(const float4*)(z_table + base + 4);
        half8 h;
        h[0]=(_Float16)f0.x; h[1]=(_Float16)f0.y; h[2]=(_Float16)f0.z; h[3]=(_Float16)f0.w;
        h[4]=(_Float16)f1.x; h[5]=(_Float16)f1.y; h[6]=(_Float16)f1.z; h[7]=(_Float16)f1.w;
        *(half8*)(zt16 + base) = h;
    } else if (b < 890) {
        const int base = (b - 826) * 1024 + tid * 4;
        *(int4*)(cnt + base) = make_int4(0, 0, 0, 0);
        if (b == 826 && tid < 128) flags[tid] = 0;
    } else {
        const int i = (b - 890) * 256 + tid;
        zn2[i] = make_int2(z[i], node_id[i]);
    }
}

// ---------------------------------------------------------------------------
// 2. Projection GEMM (MFMA), both segments in one dispatch.
// ---------------------------------------------------------------------------
__global__ __launch_bounds__(256) void proj_mfma_kernel(
    const float* __restrict__ dtab, const float* __restrict__ ctab,
    const _Float16* __restrict__ WdT, const _Float16* __restrict__ WcT,
    _Float16* __restrict__ proj)
{
    __shared__ _Float16 Alds[128 * 40];
    __shared__ _Float16 Blds[128 * 40];
    const int blk = blockIdx.x;
    const float* tab; const _Float16* WT; int base, M, bm;
    if (blk < 16) { tab = dtab; WT = WdT; base = 0;           M = NUM_DIS + 1;             bm = blk * 128; }
    else          { tab = ctab; WT = WcT; base = NUM_DIS + 1; M = G_NODES_N - NUM_DIS - 1; bm = (blk - 16) * 128; }
    const int tid  = threadIdx.x;
    const int wave = tid >> 6, lane = tid & 63;
    const int q    = lane >> 4, l16 = lane & 15;
    const int mbase = (wave & 1) * 64, nbase = (wave >> 1) * 64;
    const int r = tid >> 1, s = tid & 1;

    f32x4 acc[4][4] = {};

    for (int kc = 0; kc < 16; ++kc) {
        const int k0 = kc * 32;
        const int arow = min(bm + r, M - 1);
        const float* gA = tab + (size_t)(base + arow) * D_FEAT + k0 + s * 16;
        const _Float16* gB = WT + (size_t)r * D_FEAT + k0 + s * 16;
        const float4 f0 = ((const float4*)gA)[0];
        const float4 f1 = ((const float4*)gA)[1];
        const float4 f2 = ((const float4*)gA)[2];
        const float4 f3 = ((const float4*)gA)[3];
        const half8 hb0 = *(const half8*)gB;
        const half8 hb1 = *(const half8*)(gB + 8);
        half8 h0, h1;
        h0[0]=(_Float16)f0.x; h0[1]=(_Float16)f0.y; h0[2]=(_Float16)f0.z; h0[3]=(_Float16)f0.w;
        h0[4]=(_Float16)f1.x; h0[5]=(_Float16)f1.y; h0[6]=(_Float16)f1.z; h0[7]=(_Float16)f1.w;
        h1[0]=(_Float16)f2.x; h1[1]=(_Float16)f2.y; h1[2]=(_Float16)f2.z; h1[3]=(_Float16)f2.w;
        h1[4]=(_Float16)f3.x; h1[5]=(_Float16)f3.y; h1[6]=(_Float16)f3.z; h1[7]=(_Float16)f3.w;
        __syncthreads();
        *(half8*)&Alds[r * 40 + s * 16]     = h0;
        *(half8*)&Alds[r * 40 + s * 16 + 8] = h1;
        *(half8*)&Blds[r * 40 + s * 16]     = hb0;
        *(half8*)&Blds[r * 40 + s * 16 + 8] = hb1;
        __syncthreads();
        half8 a[4], b[4];
        #pragma unroll
        for (int i = 0; i < 4; ++i)
            a[i] = *(const half8*)&Alds[(mbase + i * 16 + l16) * 40 + q * 8];
        #pragma unroll
        for (int j = 0; j < 4; ++j)
            b[j] = *(const half8*)&Blds[(nbase + j * 16 + l16) * 40 + q * 8];
        #pragma unroll
        for (int i = 0; i < 4; ++i)
            #pragma unroll
            for (int j = 0; j < 4; ++j)
                acc[i][j] = __builtin_amdgcn_mfma_f32_16x16x32_f16(a[i], b[j], acc[i][j], 0, 0, 0);
    }

    #pragma unroll
    for (int j = 0; j < 4; ++j) {
        const int colg = nbase + j * 16 + l16;   // 0..127
        #pragma unroll
        for (int i = 0; i < 4; ++i) {
            #pragma unroll
            for (int rr = 0; rr < 4; ++rr) {
                const int row = bm + mbase + i * 16 + q * 4 + rr;
                if (row < M)
                    proj[(size_t)(base + row) * IN_DIM + colg] = (_Float16)acc[i][j][rr];
            }
        }
    }
}

// ---------------------------------------------------------------------------
// 3. CSR build: hist -> fused ALL-PUBLISH scan -> scatter
// ---------------------------------------------------------------------------
__global__ __launch_bounds__(256) void hist_kernel(
    const int* __restrict__ dst, int* __restrict__ cnt)
{
    const int e = blockIdx.x * 256 + threadIdx.x;
    if (e < N_EDGES) atomicAdd(&cnt[dst[e]], 1);
}

// 64 blocks, all co-resident (sole kernel, 64 << 256 CUs).
// flags[0] = publish counter; flags[64+i] = block i's sum.
// Each block publishes its sum, waits ONCE for all 64, then computes its
// own exclusive prefix locally -- no serial lookback chain.
__global__ __launch_bounds__(256) void scan_fused_kernel(
    const int* __restrict__ cnt, int* __restrict__ row_ptr,
    int* __restrict__ fill, int* __restrict__ flags)
{
    __shared__ int a[256], b[256];
    __shared__ int sums[64];
    __shared__ int segbase;
    const int t = threadIdx.x;
    const int blk = blockIdx.x;
    const int base = blk * 1024 + t * 4;
    const int4 c = *(const int4*)(cnt + base);
    const int s = c.x + c.y + c.z + c.w;
    a[t] = s;
    __syncthreads();
    int* in = a; int* out = b;
    for (int off = 1; off < 256; off <<= 1) {
        out[t] = in[t] + ((t >= off) ? in[t - off] : 0);
        __syncthreads();
        int* tmp = in; in = out; out = tmp;
    }
    // publish this block's total, then one global rendezvous
    if (t == 0) {
        atomicExch(&flags[64 + blk], in[255]);
        __threadfence();
        atomicAdd(&flags[0], 1);
        while (atomicAdd(&flags[0], 0) < 64) {}
    }
    __syncthreads();
    if (t < 64) sums[t] = atomicAdd(&flags[64 + t], 0);
    __syncthreads();
    if (t == 0) {
        int pfx = 0;
        for (int i = 0; i < blk; ++i) pfx += sums[i];
        segbase = pfx;
        if (blk == 63) {
            int tot = pfx;
            for (int i = blk; i < 64; ++i) tot += sums[i];
            row_ptr[N_NODES] = tot;
        }
    }
    __syncthreads();
    const int run = in[t] - s + segbase;
    int4 r;
    r.x = run; r.y = run + c.x; r.z = r.y + c.y; r.w = r.z + c.z;
    *(int4*)(row_ptr + base) = r;
    *(int4*)(fill + base) = r;
}

__global__ __launch_bounds__(256) void scatter_kernel(
    const int* __restrict__ src, const int* __restrict__ dst,
    int* __restrict__ fill, int* __restrict__ col)
{
    const int e = blockIdx.x * 256 + threadIdx.x;
    if (e < N_EDGES) {
        const int pos = atomicAdd(&fill[dst[e]], 1);
        col[pos] = src[e];
    }
}

// ---------------------------------------------------------------------------
// 4. Fused GIN: table-gather aggregation + both GIN GEMMs, H1 stays in LDS.
//    Gather sources are f16 + L2-resident: zt16 (1MB) + proj (2.5MB) + zn2.
// ---------------------------------------------------------------------------
__global__ __launch_bounds__(256) void gin_fused_kernel(
    const int* __restrict__ row_ptr, const int* __restrict__ colv,
    const int2* __restrict__ zn2,
    const _Float16* __restrict__ zt16, const _Float16* __restrict__ proj,
    const _Float16* __restrict__ W12P,
    const float* __restrict__ b1, const float* __restrict__ b2,
    _Float16* __restrict__ H)
{
    __shared__ _Float16 Apanel[32 * 264];   // [row][k], pad 264
    __shared__ _Float16 Blds[2][8192];      // [ks4][n256][8]

    const int bm   = blockIdx.x * 32;
    const int tid  = threadIdx.x;
    const int wave = tid >> 6, lane = tid & 63;
    const int q    = lane >> 4, l16 = lane & 15;
    const int nbase = wave * 64;

    auto stage = [&](int c, int buf) {
        const _Float16* src = W12P + (size_t)c * 8192;
        #pragma unroll
        for (int tt = 0; tt < 4; ++tt) {
            const int seg = (wave * 4 + tt) * 64 + lane;
            __builtin_amdgcn_global_load_lds((as1_void*)(src + seg * 8),
                (as3_void*)&Blds[buf][(wave * 4 + tt) * 64 * 8], 16, 0, 0);
        }
    };

    stage(0, 0);   // chunk-0 DMA overlaps the gather phase

    // ---- phase 0: gather (self + neighbor sum), all-f16 sources ----
    {
        const int r = tid >> 3, p = tid & 7;    // row 0..31, dim-slice 0..7
        const int gr = bm + r;
        const int beg = row_ptr[gr], end = row_ptr[gr + 1];
        float za[16], pa[16];
        {
            const int2 zn = zn2[gr];
            const half8* zp = (const half8*)(zt16 + (size_t)zn.x * IN_DIM + p * 16);
            const half8* pp = (const half8*)(proj + (size_t)zn.y * IN_DIM + p * 16);
            const half8 z0 = zp[0], z1 = zp[1], p0 = pp[0], p1 = pp[1];
            #pragma unroll
            for (int i = 0; i < 8; ++i) {
                za[i] = (float)z0[i]; za[8 + i] = (float)z1[i];
                pa[i] = (float)p0[i]; pa[8 + i] = (float)p1[i];
            }
        }
        for (int e = beg; e < end; ++e) {
            const int2 zn = zn2[colv[e]];
            const half8* zp = (const half8*)(zt16 + (size_t)zn.x * IN_DIM + p * 16);
            const half8* pp = (const half8*)(proj + (size_t)zn.y * IN_DIM + p * 16);
            const half8 z0 = zp[0], z1 = zp[1], p0 = pp[0], p1 = pp[1];
            #pragma unroll
            for (int i = 0; i < 8; ++i) {
                za[i] += (float)z0[i]; za[8 + i] += (float)z1[i];
                pa[i] += (float)p0[i]; pa[8 + i] += (float)p1[i];
            }
        }
        half8 oz0, oz1, op0, op1;
        #pragma unroll
        for (int i = 0; i < 8; ++i) {
            oz0[i] = (_Float16)za[i];     oz1[i] = (_Float16)za[8 + i];
            op0[i] = (_Float16)pa[i];     op1[i] = (_Float16)pa[8 + i];
        }
        *(half8*)&Apanel[r * 264 + p * 16]           = oz0;
        *(half8*)&Apanel[r * 264 + p * 16 + 8]       = oz1;
        *(half8*)&Apanel[r * 264 + 128 + p * 16]     = op0;
        *(half8*)&Apanel[r * 264 + 128 + p * 16 + 8] = op1;
    }
    __syncthreads();   // gather visible + chunk-0 DMA drained

    f32x4 acc[2][4] = {};
    int pb = 0;
    for (int c = 0; c < 16; ++c) {
        if (c + 1 < 16) stage(c + 1, pb ^ 1);
        if (c == 8) {
            #pragma unroll
            for (int j = 0; j < 4; ++j) {
                const int colg = nbase + j * 16 + l16;
                const float bv = b1[colg];
                #pragma unroll
                for (int i = 0; i < 2; ++i)
                    #pragma unroll
                    for (int rr = 0; rr < 4; ++rr) {
                        const float v = fmaxf(acc[i][j][rr] + bv, 0.0f);
                        Apanel[(i * 16 + q * 4 + rr) * 264 + colg] = (_Float16)v;
                        acc[i][j][rr] = 0.0f;
                    }
            }
            __syncthreads();
        }
        const int kl = (c & 7) * 32;
        half8 a[2], b[4];
        #pragma unroll
        for (int i = 0; i < 2; ++i)
            a[i] = *(const half8*)&Apanel[(i * 16 + l16) * 264 + kl + q * 8];
        #pragma unroll
        for (int j = 0; j < 4; ++j)
            b[j] = *(const half8*)&Blds[pb][(q * 256 + nbase + j * 16 + l16) * 8];
        #pragma unroll
        for (int i = 0; i < 2; ++i)
            #pragma unroll
            for (int j = 0; j < 4; ++j)
                acc[i][j] = __builtin_amdgcn_mfma_f32_16x16x32_f16(a[i], b[j], acc[i][j], 0, 0, 0);
        __syncthreads();
        pb ^= 1;
    }

    #pragma unroll
    for (int j = 0; j < 4; ++j) {
        const int colg = nbase + j * 16 + l16;
        const float bv = b2[colg];
        #pragma unroll
        for (int i = 0; i < 2; ++i)
            #pragma unroll
            for (int rr = 0; rr < 4; ++rr) {
                const int rowg = bm + i * 16 + q * 4 + rr;
                H[(size_t)rowg * HID + colg] = (_Float16)(acc[i][j][rr] + bv);
            }
    }
}

// ---------------------------------------------------------------------------
// 5. CSR gather-aggregation (SAGE mean): 32 lanes/row (16B loads).
// ---------------------------------------------------------------------------
__global__ __launch_bounds__(256) void csr_agg_kernel(
    const int* __restrict__ row_ptr, const int* __restrict__ col,
    const _Float16* __restrict__ F, _Float16* __restrict__ OUT)
{
    const int t = blockIdx.x * 256 + threadIdx.x;
    const int d = t >> 5;
    const int q = t & 31;
    const int beg = row_ptr[d];
    const int end = row_ptr[d + 1];
    float acc[8] = {0.f,0.f,0.f,0.f,0.f,0.f,0.f,0.f};
    int e = beg;
    for (; e + 4 <= end; e += 4) {
        const int s0 = col[e],     s1 = col[e + 1];
        const int s2 = col[e + 2], s3 = col[e + 3];
        const half8 v0 = *(const half8*)(F + (size_t)s0 * HID + q * 8);
        const half8 v1 = *(const half8*)(F + (size_t)s1 * HID + q * 8);
        const half8 v2 = *(const half8*)(F + (size_t)s2 * HID + q * 8);
        const half8 v3 = *(const half8*)(F + (size_t)s3 * HID + q * 8);
        #pragma unroll
        for (int i = 0; i < 8; ++i)
            acc[i] += ((float)v0[i] + (float)v1[i]) + ((float)v2[i] + (float)v3[i]);
    }
    for (; e < end; ++e) {
        const half8 v0 = *(const half8*)(F + (size_t)col[e] * HID + q * 8);
        #pragma unroll
        for (int i = 0; i < 8; ++i) acc[i] += (float)v0[i];
    }
    const float rs = 1.0f / fmaxf((float)(end - beg), 1.0f);
    half8 o;
    #pragma unroll
    for (int i = 0; i < 8; ++i) o[i] = (_Float16)(acc[i] * rs);
    *(half8*)(OUT + (size_t)d * HID + q * 8) = o;
}

// ---------------------------------------------------------------------------
// 6. MFMA f16 GEMM (SAGE): C = [A1|A2] @ [B1;B2] + bias, K=512 -> f16
// ---------------------------------------------------------------------------
__global__ __launch_bounds__(256) void mfma_gemm_kernel(
    const _Float16* __restrict__ A1, const _Float16* __restrict__ A2,
    const _Float16* __restrict__ B1T, const _Float16* __restrict__ B2T,
    const float* __restrict__ bias, _Float16* __restrict__ Ch)
{
    __shared__ _Float16 Alds[128 * 32];
    __shared__ _Float16 Blds[128 * 32];
    const int bm   = blockIdx.x * 128;
    const int bn   = blockIdx.y * 128;
    const int tid  = threadIdx.x;
    const int wave = tid >> 6, lane = tid & 63;
    const int q    = lane >> 4, l16 = lane & 15;
    const int mbase = (wave & 1) * 64, nbase = (wave >> 1) * 64;

    f32x4 acc[4][4] = {};

    for (int kc = 0; kc < 16; ++kc) {
        const int k0 = (kc & 7) * 32;
        const _Float16* Abase = (kc < 8) ? A1 : A2;
        const _Float16* Bbase = (kc < 8) ? B1T : B2T;
        __syncthreads();
        #pragma unroll
        for (int t = 0; t < 2; ++t) {
            const int i   = wave * 128 + t * 64 + lane;
            const int row = i >> 2, s = i & 3;
            const _Float16* gA = Abase + (size_t)(bm + row) * HID + k0 + s * 8;
            const _Float16* gB = Bbase + (size_t)(bn + row) * HID + k0 + s * 8;
            __builtin_amdgcn_global_load_lds(
                (as1_void*)gA, (as3_void*)&Alds[(wave * 128 + t * 64) * 8], 16, 0, 0);
            __builtin_amdgcn_global_load_lds(
                (as1_void*)gB, (as3_void*)&Blds[(wave * 128 + t * 64) * 8], 16, 0, 0);
        }
        __syncthreads();
        half8 a[4], b[4];
        #pragma unroll
        for (int i = 0; i < 4; ++i)
            a[i] = *(const half8*)&Alds[(mbase + i * 16 + l16) * 32 + q * 8];
        #pragma unroll
        for (int j = 0; j < 4; ++j)
            b[j] = *(const half8*)&Blds[(nbase + j * 16 + l16) * 32 + q * 8];
        #pragma unroll
        for (int i = 0; i < 4; ++i)
            #pragma unroll
            for (int j = 0; j < 4; ++j)
                acc[i][j] = __builtin_amdgcn_mfma_f32_16x16x32_f16(a[i], b[j], acc[i][j], 0, 0, 0);
    }

    #pragma unroll
    for (int j = 0; j < 4; ++j) {
        const int colg = bn + nbase + j * 16 + l16;
        const float bv = bias[colg];
        #pragma unroll
        for (int i = 0; i < 4; ++i) {
            #pragma unroll
            for (int rr = 0; rr < 4; ++rr) {
                const int rowg = bm + mbase + i * 16 + q * 4 + rr;
                Ch[(size_t)rowg * HID + colg] = (_Float16)(acc[i][j][rr] + bv);
            }
        }
    }
}

// ---------------------------------------------------------------------------
// 7a. Parallel partial max-pool.
// ---------------------------------------------------------------------------
__global__ __launch_bounds__(256) void pool_part_kernel(
    const _Float16* __restrict__ H2, const int* __restrict__ gid,
    float* __restrict__ Gpart)
{
    const int g = blockIdx.y;
    const int sp = blockIdx.x;
    const int j = threadIdx.x;
    int lo = 0, hi = N_NODES;
    while (lo < hi) { const int mid = (lo + hi) >> 1; if (gid[mid] < g) lo = mid + 1; else hi = mid; }
    const int start = lo;
    hi = N_NODES;
    while (lo < hi) { const int mid = (lo + hi) >> 1; if (gid[mid] < g + 1) lo = mid + 1; else hi = mid; }
    const int end = lo;
    float m = -INFINITY;
    for (int i = start + sp; i < end; i += POOL_SPLIT)
        m = fmaxf(m, (float)H2[(size_t)i * HID + j]);
    Gpart[((size_t)g * POOL_SPLIT + sp) * HID + j] = m;
}

// ---------------------------------------------------------------------------
// 7b. Head: reduce partials + MLP.
// ---------------------------------------------------------------------------
__global__ __launch_bounds__(256) void head_kernel(
    const float* __restrict__ Gpart,
    const float* __restrict__ W1, const float* __restrict__ b1,
    const float* __restrict__ W2, const float* __restrict__ b2,
    float* __restrict__ out)
{
    const int g = blockIdx.x;
    const int j = threadIdx.x;
    __shared__ float row[HID];
    __shared__ float red[HID];
    float m = -INFINITY;
    #pragma unroll
    for (int sp = 0; sp < POOL_SPLIT; ++sp)
        m = fmaxf(m, Gpart[((size_t)g * POOL_SPLIT + sp) * HID + j]);
    row[j] = (m == -INFINITY) ? 0.0f : m;
    __syncthreads();
    float acc = b1[j];
    #pragma unroll 8
    for (int k = 0; k < HID; ++k)
        acc = fmaf(row[k], W1[k * HID + j], acc);
    acc = fmaxf(acc, 0.f);
    red[j] = acc * W2[j];
    __syncthreads();
    for (int s = 128; s > 0; s >>= 1) {
        if (j < s) red[j] += red[j + s];
        __syncthreads();
    }
    if (j == 0) out[g] = red[0] + b2[0];
}

// ---------------------------------------------------------------------------
extern "C" void kernel_launch(void* const* d_in, const int* in_sizes, int n_in,
                              void* d_out, int out_size, void* d_ws, size_t ws_size,
                              hipStream_t stream)
{
    const int*   z         = (const int*)d_in[0];
    const int*   node_id   = (const int*)d_in[1];
    const int*   src       = (const int*)d_in[2];
    const int*   dst       = (const int*)d_in[3];
    const int*   graph_ids = (const int*)d_in[4];
    const float* z_table   = (const float*)d_in[5];
    const float* d_feat    = (const float*)d_in[6];
    const float* c_feat    = (const float*)d_in[7];
    const float* Wd        = (const float*)d_in[8];
    const float* Wc        = (const float*)d_in[9];
    const float* gin_W1    = (const float*)d_in[10];
    const float* gin_b1    = (const float*)d_in[11];
    const float* gin_W2    = (const float*)d_in[12];
    const float* gin_b2    = (const float*)d_in[13];
    const float* sage_Wself  = (const float*)d_in[14];
    const float* sage_Wneigh = (const float*)d_in[15];
    const float* sage_b    = (const float*)d_in[16];
    const float* lin1_W    = (const float*)d_in[17];
    const float* lin1_b    = (const float*)d_in[18];
    const float* lin2_W    = (const float*)d_in[19];
    const float* lin2_b    = (const float*)d_in[20];
    float* out = (float*)d_out;

    // ---- workspace carve-up ----
    const size_t NH = (size_t)N_NODES * HID;
    char* wsb = (char*)d_ws;
    _Float16* Hh   = (_Float16*)wsb;                     wsb += NH * 2;
    _Float16* AGGh = (_Float16*)wsb;                     wsb += NH * 2;
    _Float16* H2h  = (_Float16*)wsb;                     wsb += NH * 2;
    _Float16* projh= (_Float16*)wsb;                     wsb += (size_t)G_NODES_N * IN_DIM * 2;
    _Float16* W12P = (_Float16*)wsb;                     wsb += 16 * 8192 * 2;
    _Float16* WsT  = (_Float16*)wsb;                     wsb += HID * HID * 2;
    _Float16* WnT  = (_Float16*)wsb;                     wsb += HID * HID * 2;
    _Float16* WdT  = (_Float16*)wsb;                     wsb += D_FEAT * IN_DIM * 2;
    _Float16* WcT  = (_Float16*)wsb;                     wsb += D_FEAT * IN_DIM * 2;
    _Float16* zt16 = (_Float16*)wsb;                     wsb += (size_t)MAX_Z * IN_DIM * 2;
    int2* zn2      = (int2*)wsb;                         wsb += (size_t)N_NODES * 8;
    float* Gpart   = (float*)wsb;                        wsb += (size_t)N_GRAPHS * POOL_SPLIT * HID * 4;
    int* row_ptr   = (int*)wsb;                          wsb += (N_NODES + 4) * 4;
    int* cnt       = (int*)wsb;                          wsb += N_NODES * 4;
    int* fill      = (int*)wsb;                          wsb += N_NODES * 4;
    int* col       = (int*)wsb;                          wsb += N_EDGES * 4;
    int* flags     = (int*)wsb;                          wsb += 128 * 4;

    // ---- prep: all converts/swizzles/zeroing in one dispatch ----
    prep_kernel<<<1146, 256, 0, stream>>>(
        sage_Wself, sage_Wneigh, Wd, Wc, gin_W1, gin_W2, z_table, z, node_id,
        WsT, WnT, WdT, WcT, W12P, zt16, zn2, cnt, flags);

    // ---- CSR build ----
    hist_kernel<<<N_EDGES / 256, 256, 0, stream>>>(dst, cnt);
    scan_fused_kernel<<<64, 256, 0, stream>>>(cnt, row_ptr, fill, flags);
    scatter_kernel<<<N_EDGES / 256, 256, 0, stream>>>(src, dst, fill, col);

    // ---- projection table via MFMA ----
    proj_mfma_kernel<<<16 + 63, 256, 0, stream>>>(d_feat, c_feat, WdT, WcT, projh);

    // ---- fused GIN: gather + MLP, H1 stays in LDS ----
    gin_fused_kernel<<<N_NODES / 32, 256, 0, stream>>>(
        row_ptr, col, zn2, zt16, projh, W12P, gin_b1, gin_b2, Hh);

    // ---- SAGE mean aggregation ----
    csr_agg_kernel<<<(N_NODES * 32) / 256, 256, 0, stream>>>(row_ptr, col, Hh, AGGh);

    // ---- SAGE: H2 = H@Wself + AGG@Wneigh + b  (K=512) ----
    dim3 ggrid(N_NODES / 128, HID / 128);
    mfma_gemm_kernel<<<ggrid, 256, 0, stream>>>(Hh, AGGh, WsT, WnT, sage_b, H2h);

    // ---- parallel max pool + head ----
    dim3 pgrid(POOL_SPLIT, N_GRAPHS);
    pool_part_kernel<<<pgrid, 256, 0, stream>>>(H2h, graph_ids, Gpart);
    head_kernel<<<N_GRAPHS, 256, 0, stream>>>(Gpart, lin1_W, lin1_b, lin2_W, lin2_b, out);
}

// Round 12
// 366.895 us; speedup vs baseline: 1.2188x; 1.0335x over previous
//
#include <hip/hip_runtime.h>
#include <hip/hip_bf16.h>

#define N_NODES     65536
#define N_EDGES     524288
#define N_GRAPHS    512
#define G_NODES_N   10000
#define NUM_DIS     2000
#define IN_DIM      128
#define HID         256
#define D_FEAT      512
#define MAX_Z       4000
#define POOL_SPLIT  8

typedef _Float16 half8 __attribute__((ext_vector_type(8)));
typedef float    f32x4 __attribute__((ext_vector_type(4)));

typedef __attribute__((address_space(1))) const void as1_void;
typedef __attribute__((address_space(3))) void       as3_void;

// ---------------------------------------------------------------------------
// 1. ONE prep dispatch: all weight converts/swizzles + zt16 + zn2 + zeroing.
// ---------------------------------------------------------------------------
__global__ __launch_bounds__(256) void prep_kernel(
    const float* __restrict__ Ws, const float* __restrict__ Wn,
    const float* __restrict__ Wd, const float* __restrict__ Wc,
    const float* __restrict__ W1, const float* __restrict__ W2,
    const float* __restrict__ z_table,
    const int* __restrict__ z, const int* __restrict__ node_id,
    _Float16* __restrict__ WsT, _Float16* __restrict__ WnT,
    _Float16* __restrict__ WdT, _Float16* __restrict__ WcT,
    _Float16* __restrict__ W12P, _Float16* __restrict__ zt16,
    int2* __restrict__ zn2, int* __restrict__ cnt, int* __restrict__ flags)
{
    const int b = blockIdx.x;
    const int tid = threadIdx.x;
    if (b < 64) {
        __shared__ float tile[64][65];
        const float* W; _Float16* T; int K, N, k0, n0;
        if (b < 32) {
            const int mat = b >> 4, t = b & 15;
            K = HID; N = HID; k0 = (t >> 2) * 64; n0 = (t & 3) * 64;
            W = (mat == 0) ? Ws : Wn;
            T = (mat == 0) ? WsT : WnT;
        } else {
            const int bb = b - 32;
            const int mat = bb >> 4, t = bb & 15;
            K = D_FEAT; N = IN_DIM; k0 = (t >> 1) * 64; n0 = (t & 1) * 64;
            W = (mat == 0) ? Wd : Wc;
            T = (mat == 0) ? WdT : WcT;
        }
        const int tx = tid & 63, ty = tid >> 6;
        #pragma unroll
        for (int r = 0; r < 64; r += 4)
            tile[r + ty][tx] = W[(size_t)(k0 + r + ty) * N + n0 + tx];
        __syncthreads();
        #pragma unroll
        for (int c = 0; c < 64; c += 4)
            T[(size_t)(n0 + c + ty) * K + k0 + tx] = (_Float16)tile[tx][c + ty];
    } else if (b < 576) {
        const int bb = b - 64;              // 0..511
        const int mat = bb >> 8;            // 0: W1, 1: W2
        const int k = bb & 255;
        const int n = tid;
        const float* W = mat ? W2 : W1;
        const float v = W[(size_t)k * HID + n];
        const size_t idx = (size_t)(mat * 8 + (k >> 5)) * 8192
                         + (size_t)((((k >> 3) & 3) * 256 + n) * 8 + (k & 7));
        W12P[idx] = (_Float16)v;
    } else if (b < 826) {
        const size_t base = ((size_t)(b - 576) * 256 + tid) * 8;  // < 512000
        const float4 f0 = *(const float4*)(z_table + base);
        const float4 f1 = *(const float4*)(z_table + base + 4);
        half8 h;
        h[0]=(_Float16)f0.x; h[1]=(_Float16)f0.y; h[2]=(_Float16)f0.z; h[3]=(_Float16)f0.w;
        h[4]=(_Float16)f1.x; h[5]=(_Float16)f1.y; h[6]=(_Float16)f1.z; h[7]=(_Float16)f1.w;
        *(half8*)(zt16 + base) = h;
    } else if (b < 890) {
        const int base = (b - 826) * 1024 + tid * 4;
        *(int4*)(cnt + base) = make_int4(0, 0, 0, 0);
        if (b == 826 && tid < 128) flags[tid] = 0;
    } else {
        const int i = (b - 890) * 256 + tid;
        zn2[i] = make_int2(z[i], node_id[i]);
    }
}

// ---------------------------------------------------------------------------
// 2. Projection GEMM (MFMA), both segments in one dispatch.
// ---------------------------------------------------------------------------
__global__ __launch_bounds__(256) void proj_mfma_kernel(
    const float* __restrict__ dtab, const float* __restrict__ ctab,
    const _Float16* __restrict__ WdT, const _Float16* __restrict__ WcT,
    _Float16* __restrict__ proj)
{
    __shared__ _Float16 Alds[128 * 40];
    __shared__ _Float16 Blds[128 * 40];
    const int blk = blockIdx.x;
    const float* tab; const _Float16* WT; int base, M, bm;
    if (blk < 16) { tab = dtab; WT = WdT; base = 0;           M = NUM_DIS + 1;             bm = blk * 128; }
    else          { tab = ctab; WT = WcT; base = NUM_DIS + 1; M = G_NODES_N - NUM_DIS - 1; bm = (blk - 16) * 128; }
    const int tid  = threadIdx.x;
    const int wave = tid >> 6, lane = tid & 63;
    const int q    = lane >> 4, l16 = lane & 15;
    const int mbase = (wave & 1) * 64, nbase = (wave >> 1) * 64;
    const int r = tid >> 1, s = tid & 1;

    f32x4 acc[4][4] = {};

    for (int kc = 0; kc < 16; ++kc) {
        const int k0 = kc * 32;
        const int arow = min(bm + r, M - 1);
        const float* gA = tab + (size_t)(base + arow) * D_FEAT + k0 + s * 16;
        const _Float16* gB = WT + (size_t)r * D_FEAT + k0 + s * 16;
        const float4 f0 = ((const float4*)gA)[0];
        const float4 f1 = ((const float4*)gA)[1];
        const float4 f2 = ((const float4*)gA)[2];
        const float4 f3 = ((const float4*)gA)[3];
        const half8 hb0 = *(const half8*)gB;
        const half8 hb1 = *(const half8*)(gB + 8);
        half8 h0, h1;
        h0[0]=(_Float16)f0.x; h0[1]=(_Float16)f0.y; h0[2]=(_Float16)f0.z; h0[3]=(_Float16)f0.w;
        h0[4]=(_Float16)f1.x; h0[5]=(_Float16)f1.y; h0[6]=(_Float16)f1.z; h0[7]=(_Float16)f1.w;
        h1[0]=(_Float16)f2.x; h1[1]=(_Float16)f2.y; h1[2]=(_Float16)f2.z; h1[3]=(_Float16)f2.w;
        h1[4]=(_Float16)f3.x; h1[5]=(_Float16)f3.y; h1[6]=(_Float16)f3.z; h1[7]=(_Float16)f3.w;
        __syncthreads();
        *(half8*)&Alds[r * 40 + s * 16]     = h0;
        *(half8*)&Alds[r * 40 + s * 16 + 8] = h1;
        *(half8*)&Blds[r * 40 + s * 16]     = hb0;
        *(half8*)&Blds[r * 40 + s * 16 + 8] = hb1;
        __syncthreads();
        half8 a[4], b[4];
        #pragma unroll
        for (int i = 0; i < 4; ++i)
            a[i] = *(const half8*)&Alds[(mbase + i * 16 + l16) * 40 + q * 8];
        #pragma unroll
        for (int j = 0; j < 4; ++j)
            b[j] = *(const half8*)&Blds[(nbase + j * 16 + l16) * 40 + q * 8];
        #pragma unroll
        for (int i = 0; i < 4; ++i)
            #pragma unroll
            for (int j = 0; j < 4; ++j)
                acc[i][j] = __builtin_amdgcn_mfma_f32_16x16x32_f16(a[i], b[j], acc[i][j], 0, 0, 0);
    }

    #pragma unroll
    for (int j = 0; j < 4; ++j) {
        const int colg = nbase + j * 16 + l16;   // 0..127
        #pragma unroll
        for (int i = 0; i < 4; ++i) {
            #pragma unroll
            for (int rr = 0; rr < 4; ++rr) {
                const int row = bm + mbase + i * 16 + q * 4 + rr;
                if (row < M)
                    proj[(size_t)(base + row) * IN_DIM + colg] = (_Float16)acc[i][j][rr];
            }
        }
    }
}

// ---------------------------------------------------------------------------
// 3. CSR build: hist -> fused ALL-PUBLISH scan -> scatter (+ colzn pregather)
// ---------------------------------------------------------------------------
__global__ __launch_bounds__(256) void hist_kernel(
    const int* __restrict__ dst, int* __restrict__ cnt)
{
    const int e = blockIdx.x * 256 + threadIdx.x;
    if (e < N_EDGES) atomicAdd(&cnt[dst[e]], 1);
}

// 64 blocks, all co-resident. One rendezvous, then local prefix of 64 sums.
__global__ __launch_bounds__(256) void scan_fused_kernel(
    const int* __restrict__ cnt, int* __restrict__ row_ptr,
    int* __restrict__ fill, int* __restrict__ flags)
{
    __shared__ int a[256], b[256];
    __shared__ int sums[64];
    __shared__ int segbase;
    const int t = threadIdx.x;
    const int blk = blockIdx.x;
    const int base = blk * 1024 + t * 4;
    const int4 c = *(const int4*)(cnt + base);
    const int s = c.x + c.y + c.z + c.w;
    a[t] = s;
    __syncthreads();
    int* in = a; int* out = b;
    for (int off = 1; off < 256; off <<= 1) {
        out[t] = in[t] + ((t >= off) ? in[t - off] : 0);
        __syncthreads();
        int* tmp = in; in = out; out = tmp;
    }
    if (t == 0) {
        atomicExch(&flags[64 + blk], in[255]);
        __threadfence();
        atomicAdd(&flags[0], 1);
        while (atomicAdd(&flags[0], 0) < 64) {}
    }
    __syncthreads();
    if (t < 64) sums[t] = atomicAdd(&flags[64 + t], 0);
    __syncthreads();
    if (t == 0) {
        int pfx = 0;
        for (int i = 0; i < blk; ++i) pfx += sums[i];
        segbase = pfx;
        if (blk == 63) {
            int tot = pfx;
            for (int i = blk; i < 64; ++i) tot += sums[i];
            row_ptr[N_NODES] = tot;
        }
    }
    __syncthreads();
    const int run = in[t] - s + segbase;
    int4 r;
    r.x = run; r.y = run + c.x; r.z = r.y + c.y; r.w = r.z + c.z;
    *(int4*)(row_ptr + base) = r;
    *(int4*)(fill + base) = r;
}

// Scatter also pre-gathers colzn[pos] = zn2[src[e]] so the GIN gather's
// index data is contiguous (kills one latency level + redundant reads).
__global__ __launch_bounds__(256) void scatter_kernel(
    const int* __restrict__ src, const int* __restrict__ dst,
    const int2* __restrict__ zn2,
    int* __restrict__ fill, int* __restrict__ col, int2* __restrict__ colzn)
{
    const int e = blockIdx.x * 256 + threadIdx.x;
    if (e < N_EDGES) {
        const int s = src[e];
        const int pos = atomicAdd(&fill[dst[e]], 1);
        col[pos] = s;
        colzn[pos] = zn2[s];
    }
}

// ---------------------------------------------------------------------------
// 4. Fused GIN: table-gather aggregation + both GIN GEMMs, H1 stays in LDS.
//    Gather: colzn is contiguous-per-edge; table loads unrolled x2 (8 loads
//    in flight per lane).
// ---------------------------------------------------------------------------
__global__ __launch_bounds__(256) void gin_fused_kernel(
    const int* __restrict__ row_ptr, const int2* __restrict__ colzn,
    const int2* __restrict__ zn2,
    const _Float16* __restrict__ zt16, const _Float16* __restrict__ proj,
    const _Float16* __restrict__ W12P,
    const float* __restrict__ b1, const float* __restrict__ b2,
    _Float16* __restrict__ H)
{
    __shared__ _Float16 Apanel[32 * 264];   // [row][k], pad 264
    __shared__ _Float16 Blds[2][8192];      // [ks4][n256][8]

    const int bm   = blockIdx.x * 32;
    const int tid  = threadIdx.x;
    const int wave = tid >> 6, lane = tid & 63;
    const int q    = lane >> 4, l16 = lane & 15;
    const int nbase = wave * 64;

    auto stage = [&](int c, int buf) {
        const _Float16* src = W12P + (size_t)c * 8192;
        #pragma unroll
        for (int tt = 0; tt < 4; ++tt) {
            const int seg = (wave * 4 + tt) * 64 + lane;
            __builtin_amdgcn_global_load_lds((as1_void*)(src + seg * 8),
                (as3_void*)&Blds[buf][(wave * 4 + tt) * 64 * 8], 16, 0, 0);
        }
    };

    stage(0, 0);   // chunk-0 DMA overlaps the gather phase

    // ---- phase 0: gather (self + neighbor sum), all-f16 L2-resident ----
    {
        const int r = tid >> 3, p = tid & 7;    // row 0..31, dim-slice 0..7
        const int gr = bm + r;
        const int beg = row_ptr[gr], end = row_ptr[gr + 1];
        float za[16], pa[16];
        {
            const int2 zn = zn2[gr];
            const half8* zp = (const half8*)(zt16 + (size_t)zn.x * IN_DIM + p * 16);
            const half8* pp = (const half8*)(proj + (size_t)zn.y * IN_DIM + p * 16);
            const half8 z0 = zp[0], z1 = zp[1], p0 = pp[0], p1 = pp[1];
            #pragma unroll
            for (int i = 0; i < 8; ++i) {
                za[i] = (float)z0[i]; za[8 + i] = (float)z1[i];
                pa[i] = (float)p0[i]; pa[8 + i] = (float)p1[i];
            }
        }
        int e = beg;
        for (; e + 2 <= end; e += 2) {
            const int2 znA = colzn[e];
            const int2 znB = colzn[e + 1];
            const half8* zpA = (const half8*)(zt16 + (size_t)znA.x * IN_DIM + p * 16);
            const half8* ppA = (const half8*)(proj + (size_t)znA.y * IN_DIM + p * 16);
            const half8* zpB = (const half8*)(zt16 + (size_t)znB.x * IN_DIM + p * 16);
            const half8* ppB = (const half8*)(proj + (size_t)znB.y * IN_DIM + p * 16);
            const half8 zA0 = zpA[0], zA1 = zpA[1], pA0 = ppA[0], pA1 = ppA[1];
            const half8 zB0 = zpB[0], zB1 = zpB[1], pB0 = ppB[0], pB1 = ppB[1];
            #pragma unroll
            for (int i = 0; i < 8; ++i) {
                za[i]     += (float)zA0[i] + (float)zB0[i];
                za[8 + i] += (float)zA1[i] + (float)zB1[i];
                pa[i]     += (float)pA0[i] + (float)pB0[i];
                pa[8 + i] += (float)pA1[i] + (float)pB1[i];
            }
        }
        if (e < end) {
            const int2 zn = colzn[e];
            const half8* zp = (const half8*)(zt16 + (size_t)zn.x * IN_DIM + p * 16);
            const half8* pp = (const half8*)(proj + (size_t)zn.y * IN_DIM + p * 16);
            const half8 z0 = zp[0], z1 = zp[1], p0 = pp[0], p1 = pp[1];
            #pragma unroll
            for (int i = 0; i < 8; ++i) {
                za[i] += (float)z0[i]; za[8 + i] += (float)z1[i];
                pa[i] += (float)p0[i]; pa[8 + i] += (float)p1[i];
            }
        }
        half8 oz0, oz1, op0, op1;
        #pragma unroll
        for (int i = 0; i < 8; ++i) {
            oz0[i] = (_Float16)za[i];     oz1[i] = (_Float16)za[8 + i];
            op0[i] = (_Float16)pa[i];     op1[i] = (_Float16)pa[8 + i];
        }
        *(half8*)&Apanel[r * 264 + p * 16]           = oz0;
        *(half8*)&Apanel[r * 264 + p * 16 + 8]       = oz1;
        *(half8*)&Apanel[r * 264 + 128 + p * 16]     = op0;
        *(half8*)&Apanel[r * 264 + 128 + p * 16 + 8] = op1;
    }
    __syncthreads();   // gather visible + chunk-0 DMA drained

    f32x4 acc[2][4] = {};
    int pb = 0;
    for (int c = 0; c < 16; ++c) {
        if (c + 1 < 16) stage(c + 1, pb ^ 1);
        if (c == 8) {
            #pragma unroll
            for (int j = 0; j < 4; ++j) {
                const int colg = nbase + j * 16 + l16;
                const float bv = b1[colg];
                #pragma unroll
                for (int i = 0; i < 2; ++i)
                    #pragma unroll
                    for (int rr = 0; rr < 4; ++rr) {
                        const float v = fmaxf(acc[i][j][rr] + bv, 0.0f);
                        Apanel[(i * 16 + q * 4 + rr) * 264 + colg] = (_Float16)v;
                        acc[i][j][rr] = 0.0f;
                    }
            }
            __syncthreads();
        }
        const int kl = (c & 7) * 32;
        half8 a[2], b[4];
        #pragma unroll
        for (int i = 0; i < 2; ++i)
            a[i] = *(const half8*)&Apanel[(i * 16 + l16) * 264 + kl + q * 8];
        #pragma unroll
        for (int j = 0; j < 4; ++j)
            b[j] = *(const half8*)&Blds[pb][(q * 256 + nbase + j * 16 + l16) * 8];
        #pragma unroll
        for (int i = 0; i < 2; ++i)
            #pragma unroll
            for (int j = 0; j < 4; ++j)
                acc[i][j] = __builtin_amdgcn_mfma_f32_16x16x32_f16(a[i], b[j], acc[i][j], 0, 0, 0);
        __syncthreads();
        pb ^= 1;
    }

    #pragma unroll
    for (int j = 0; j < 4; ++j) {
        const int colg = nbase + j * 16 + l16;
        const float bv = b2[colg];
        #pragma unroll
        for (int i = 0; i < 2; ++i)
            #pragma unroll
            for (int rr = 0; rr < 4; ++rr) {
                const int rowg = bm + i * 16 + q * 4 + rr;
                H[(size_t)rowg * HID + colg] = (_Float16)(acc[i][j][rr] + bv);
            }
    }
}

// ---------------------------------------------------------------------------
// 5. CSR gather-aggregation (SAGE mean): 32 lanes/row (16B loads).
// ---------------------------------------------------------------------------
__global__ __launch_bounds__(256) void csr_agg_kernel(
    const int* __restrict__ row_ptr, const int* __restrict__ col,
    const _Float16* __restrict__ F, _Float16* __restrict__ OUT)
{
    const int t = blockIdx.x * 256 + threadIdx.x;
    const int d = t >> 5;
    const int q = t & 31;
    const int beg = row_ptr[d];
    const int end = row_ptr[d + 1];
    float acc[8] = {0.f,0.f,0.f,0.f,0.f,0.f,0.f,0.f};
    int e = beg;
    for (; e + 4 <= end; e += 4) {
        const int s0 = col[e],     s1 = col[e + 1];
        const int s2 = col[e + 2], s3 = col[e + 3];
        const half8 v0 = *(const half8*)(F + (size_t)s0 * HID + q * 8);
        const half8 v1 = *(const half8*)(F + (size_t)s1 * HID + q * 8);
        const half8 v2 = *(const half8*)(F + (size_t)s2 * HID + q * 8);
        const half8 v3 = *(const half8*)(F + (size_t)s3 * HID + q * 8);
        #pragma unroll
        for (int i = 0; i < 8; ++i)
            acc[i] += ((float)v0[i] + (float)v1[i]) + ((float)v2[i] + (float)v3[i]);
    }
    for (; e < end; ++e) {
        const half8 v0 = *(const half8*)(F + (size_t)col[e] * HID + q * 8);
        #pragma unroll
        for (int i = 0; i < 8; ++i) acc[i] += (float)v0[i];
    }
    const float rs = 1.0f / fmaxf((float)(end - beg), 1.0f);
    half8 o;
    #pragma unroll
    for (int i = 0; i < 8; ++i) o[i] = (_Float16)(acc[i] * rs);
    *(half8*)(OUT + (size_t)d * HID + q * 8) = o;
}

// ---------------------------------------------------------------------------
// 6. MFMA f16 GEMM (SAGE): C = [A1|A2] @ [B1;B2] + bias, K=512 -> f16
// ---------------------------------------------------------------------------
__global__ __launch_bounds__(256) void mfma_gemm_kernel(
    const _Float16* __restrict__ A1, const _Float16* __restrict__ A2,
    const _Float16* __restrict__ B1T, const _Float16* __restrict__ B2T,
    const float* __restrict__ bias, _Float16* __restrict__ Ch)
{
    __shared__ _Float16 Alds[128 * 32];
    __shared__ _Float16 Blds[128 * 32];
    const int bm   = blockIdx.x * 128;
    const int bn   = blockIdx.y * 128;
    const int tid  = threadIdx.x;
    const int wave = tid >> 6, lane = tid & 63;
    const int q    = lane >> 4, l16 = lane & 15;
    const int mbase = (wave & 1) * 64, nbase = (wave >> 1) * 64;

    f32x4 acc[4][4] = {};

    for (int kc = 0; kc < 16; ++kc) {
        const int k0 = (kc & 7) * 32;
        const _Float16* Abase = (kc < 8) ? A1 : A2;
        const _Float16* Bbase = (kc < 8) ? B1T : B2T;
        __syncthreads();
        #pragma unroll
        for (int t = 0; t < 2; ++t) {
            const int i   = wave * 128 + t * 64 + lane;
            const int row = i >> 2, s = i & 3;
            const _Float16* gA = Abase + (size_t)(bm + row) * HID + k0 + s * 8;
            const _Float16* gB = Bbase + (size_t)(bn + row) * HID + k0 + s * 8;
            __builtin_amdgcn_global_load_lds(
                (as1_void*)gA, (as3_void*)&Alds[(wave * 128 + t * 64) * 8], 16, 0, 0);
            __builtin_amdgcn_global_load_lds(
                (as1_void*)gB, (as3_void*)&Blds[(wave * 128 + t * 64) * 8], 16, 0, 0);
        }
        __syncthreads();
        half8 a[4], b[4];
        #pragma unroll
        for (int i = 0; i < 4; ++i)
            a[i] = *(const half8*)&Alds[(mbase + i * 16 + l16) * 32 + q * 8];
        #pragma unroll
        for (int j = 0; j < 4; ++j)
            b[j] = *(const half8*)&Blds[(nbase + j * 16 + l16) * 32 + q * 8];
        #pragma unroll
        for (int i = 0; i < 4; ++i)
            #pragma unroll
            for (int j = 0; j < 4; ++j)
                acc[i][j] = __builtin_amdgcn_mfma_f32_16x16x32_f16(a[i], b[j], acc[i][j], 0, 0, 0);
    }

    #pragma unroll
    for (int j = 0; j < 4; ++j) {
        const int colg = bn + nbase + j * 16 + l16;
        const float bv = bias[colg];
        #pragma unroll
        for (int i = 0; i < 4; ++i) {
            #pragma unroll
            for (int rr = 0; rr < 4; ++rr) {
                const int rowg = bm + mbase + i * 16 + q * 4 + rr;
                Ch[(size_t)rowg * HID + colg] = (_Float16)(acc[i][j][rr] + bv);
            }
        }
    }
}

// ---------------------------------------------------------------------------
// 7a. Parallel partial max-pool.
// ---------------------------------------------------------------------------
__global__ __launch_bounds__(256) void pool_part_kernel(
    const _Float16* __restrict__ H2, const int* __restrict__ gid,
    float* __restrict__ Gpart)
{
    const int g = blockIdx.y;
    const int sp = blockIdx.x;
    const int j = threadIdx.x;
    int lo = 0, hi = N_NODES;
    while (lo < hi) { const int mid = (lo + hi) >> 1; if (gid[mid] < g) lo = mid + 1; else hi = mid; }
    const int start = lo;
    hi = N_NODES;
    while (lo < hi) { const int mid = (lo + hi) >> 1; if (gid[mid] < g + 1) lo = mid + 1; else hi = mid; }
    const int end = lo;
    float m = -INFINITY;
    for (int i = start + sp; i < end; i += POOL_SPLIT)
        m = fmaxf(m, (float)H2[(size_t)i * HID + j]);
    Gpart[((size_t)g * POOL_SPLIT + sp) * HID + j] = m;
}

// ---------------------------------------------------------------------------
// 7b. Head: reduce partials + MLP.
// ---------------------------------------------------------------------------
__global__ __launch_bounds__(256) void head_kernel(
    const float* __restrict__ Gpart,
    const float* __restrict__ W1, const float* __restrict__ b1,
    const float* __restrict__ W2, const float* __restrict__ b2,
    float* __restrict__ out)
{
    const int g = blockIdx.x;
    const int j = threadIdx.x;
    __shared__ float row[HID];
    __shared__ float red[HID];
    float m = -INFINITY;
    #pragma unroll
    for (int sp = 0; sp < POOL_SPLIT; ++sp)
        m = fmaxf(m, Gpart[((size_t)g * POOL_SPLIT + sp) * HID + j]);
    row[j] = (m == -INFINITY) ? 0.0f : m;
    __syncthreads();
    float acc = b1[j];
    #pragma unroll 8
    for (int k = 0; k < HID; ++k)
        acc = fmaf(row[k], W1[k * HID + j], acc);
    acc = fmaxf(acc, 0.f);
    red[j] = acc * W2[j];
    __syncthreads();
    for (int s = 128; s > 0; s >>= 1) {
        if (j < s) red[j] += red[j + s];
        __syncthreads();
    }
    if (j == 0) out[g] = red[0] + b2[0];
}

// ---------------------------------------------------------------------------
extern "C" void kernel_launch(void* const* d_in, const int* in_sizes, int n_in,
                              void* d_out, int out_size, void* d_ws, size_t ws_size,
                              hipStream_t stream)
{
    const int*   z         = (const int*)d_in[0];
    const int*   node_id   = (const int*)d_in[1];
    const int*   src       = (const int*)d_in[2];
    const int*   dst       = (const int*)d_in[3];
    const int*   graph_ids = (const int*)d_in[4];
    const float* z_table   = (const float*)d_in[5];
    const float* d_feat    = (const float*)d_in[6];
    const float* c_feat    = (const float*)d_in[7];
    const float* Wd        = (const float*)d_in[8];
    const float* Wc        = (const float*)d_in[9];
    const float* gin_W1    = (const float*)d_in[10];
    const float* gin_b1    = (const float*)d_in[11];
    const float* gin_W2    = (const float*)d_in[12];
    const float* gin_b2    = (const float*)d_in[13];
    const float* sage_Wself  = (const float*)d_in[14];
    const float* sage_Wneigh = (const float*)d_in[15];
    const float* sage_b    = (const float*)d_in[16];
    const float* lin1_W    = (const float*)d_in[17];
    const float* lin1_b    = (const float*)d_in[18];
    const float* lin2_W    = (const float*)d_in[19];
    const float* lin2_b    = (const float*)d_in[20];
    float* out = (float*)d_out;

    // ---- workspace carve-up ----
    const size_t NH = (size_t)N_NODES * HID;
    char* wsb = (char*)d_ws;
    _Float16* Hh   = (_Float16*)wsb;                     wsb += NH * 2;
    _Float16* AGGh = (_Float16*)wsb;                     wsb += NH * 2;
    _Float16* H2h  = (_Float16*)wsb;                     wsb += NH * 2;
    _Float16* projh= (_Float16*)wsb;                     wsb += (size_t)G_NODES_N * IN_DIM * 2;
    _Float16* W12P = (_Float16*)wsb;                     wsb += 16 * 8192 * 2;
    _Float16* WsT  = (_Float16*)wsb;                     wsb += HID * HID * 2;
    _Float16* WnT  = (_Float16*)wsb;                     wsb += HID * HID * 2;
    _Float16* WdT  = (_Float16*)wsb;                     wsb += D_FEAT * IN_DIM * 2;
    _Float16* WcT  = (_Float16*)wsb;                     wsb += D_FEAT * IN_DIM * 2;
    _Float16* zt16 = (_Float16*)wsb;                     wsb += (size_t)MAX_Z * IN_DIM * 2;
    int2* zn2      = (int2*)wsb;                         wsb += (size_t)N_NODES * 8;
    int2* colzn    = (int2*)wsb;                         wsb += (size_t)N_EDGES * 8;
    float* Gpart   = (float*)wsb;                        wsb += (size_t)N_GRAPHS * POOL_SPLIT * HID * 4;
    int* row_ptr   = (int*)wsb;                          wsb += (N_NODES + 4) * 4;
    int* cnt       = (int*)wsb;                          wsb += N_NODES * 4;
    int* fill      = (int*)wsb;                          wsb += N_NODES * 4;
    int* col       = (int*)wsb;                          wsb += N_EDGES * 4;
    int* flags     = (int*)wsb;                          wsb += 128 * 4;

    // ---- prep: all converts/swizzles/zeroing in one dispatch ----
    prep_kernel<<<1146, 256, 0, stream>>>(
        sage_Wself, sage_Wneigh, Wd, Wc, gin_W1, gin_W2, z_table, z, node_id,
        WsT, WnT, WdT, WcT, W12P, zt16, zn2, cnt, flags);

    // ---- CSR build ----
    hist_kernel<<<N_EDGES / 256, 256, 0, stream>>>(dst, cnt);
    scan_fused_kernel<<<64, 256, 0, stream>>>(cnt, row_ptr, fill, flags);
    scatter_kernel<<<N_EDGES / 256, 256, 0, stream>>>(src, dst, zn2, fill, col, colzn);

    // ---- projection table via MFMA ----
    proj_mfma_kernel<<<16 + 63, 256, 0, stream>>>(d_feat, c_feat, WdT, WcT, projh);

    // ---- fused GIN: gather + MLP, H1 stays in LDS ----
    gin_fused_kernel<<<N_NODES / 32, 256, 0, stream>>>(
        row_ptr, colzn, zn2, zt16, projh, W12P, gin_b1, gin_b2, Hh);

    // ---- SAGE mean aggregation ----
    csr_agg_kernel<<<(N_NODES * 32) / 256, 256, 0, stream>>>(row_ptr, col, Hh, AGGh);

    // ---- SAGE: H2 = H@Wself + AGG@Wneigh + b  (K=512) ----
    dim3 ggrid(N_NODES / 128, HID / 128);
    mfma_gemm_kernel<<<ggrid, 256, 0, stream>>>(Hh, AGGh, WsT, WnT, sage_b, H2h);

    // ---- parallel max pool + head ----
    dim3 pgrid(POOL_SPLIT, N_GRAPHS);
    pool_part_kernel<<<pgrid, 256, 0, stream>>>(H2h, graph_ids, Gpart);
    head_kernel<<<N_GRAPHS, 256, 0, stream>>>(Gpart, lin1_W, lin1_b, lin2_W, lin2_b, out);
}